// Round 4
// baseline (638.725 us; speedup 1.0000x reference)
//
#include <hip/hip_runtime.h>
#include <hip/hip_bf16.h>
#include <hip/hip_fp16.h>
#include <math.h>

// Problem dims (fixed by reference)
#define B_  32
#define T_  512
#define F_  4096
#define H_  128
#define G4H 512           // 4*H
#define NCLS 3            // NUM_CLASSES + 1
#define M_  (B_ * T_)     // 16384 rows
#define KSTEPS 128        // F_/32

typedef _Float16 f16x8 __attribute__((ext_vector_type(8)));
typedef _Float16 f16x4 __attribute__((ext_vector_type(4)));
typedef float    f32x4 __attribute__((ext_vector_type(4)));

// async global->LDS, 16B per lane; LDS dest is wave-uniform base + lane*16
__device__ __forceinline__ void gl_lds16(const _Float16* g, _Float16* l) {
    __builtin_amdgcn_global_load_lds(
        (const __attribute__((address_space(1))) void*)(g),
        (__attribute__((address_space(3))) void*)(l), 16, 0, 0);
}

// ---------------------------------------------------------------------------
// Kernel 0b: Wk [F,4H] fp32 -> btK fp16, K-MAJOR tiles with baked-in group
// swizzle (unchanged).
// ---------------------------------------------------------------------------
__global__ __launch_bounds__(256) void cvt_wkT(
    const float* __restrict__ Wk, _Float16* __restrict__ btK)
{
    __shared__ float ls[64][65];
    const int k0 = blockIdx.x * 64;
    const int n0 = blockIdx.y * 64;
    const int tid = threadIdx.x;

    {
        int r  = tid >> 4;
        int c4 = (tid & 15) * 4;
        #pragma unroll
        for (int p = 0; p < 4; ++p) {
            float4 v = *reinterpret_cast<const float4*>(
                &Wk[(size_t)(k0 + r + p * 16) * G4H + n0 + c4]);
            ls[r + p * 16][c4 + 0] = v.x;
            ls[r + p * 16][c4 + 1] = v.y;
            ls[r + p * 16][c4 + 2] = v.z;
            ls[r + p * 16][c4 + 3] = v.w;
        }
    }
    __syncthreads();
    {
        int rn = tid >> 2;            // n within tile 0..63
        int ck = (tid & 3) * 16;      // k within tile 0,16,32,48
        f16x8 h0, h1;
        #pragma unroll
        for (int j = 0; j < 8; ++j) {
            h0[j] = (_Float16)ls[ck + j][rn];
            h1[j] = (_Float16)ls[ck + 8 + j][rn];
        }
        const int n    = n0 + rn;
        const int kg   = k0 + ck;
        const int kblk = kg >> 5;
        const int kk   = kg & 31;           // 0 or 16
        const int g0   = kk >> 3;           // 0 or 2
        const int sw   = (n >> 1) & 3;
        _Float16* base = btK + (size_t)kblk * (512 * 32) + (size_t)n * 32;
        *reinterpret_cast<f16x8*>(base + ((g0 ^ sw) << 3))       = h0;
        *reinterpret_cast<f16x8*>(base + (((g0 + 1) ^ sw) << 3)) = h1;
    }
}

// ---------------------------------------------------------------------------
// Kernel 0c: Wr [H,4H] fp32 -> wrT [4H,H] fp16 (transpose). grid (2, 8).
// Also zeroes the 256 producer/consumer flags (block (0,0)).
// ---------------------------------------------------------------------------
__global__ __launch_bounds__(256) void cvt_wrT(
    const float* __restrict__ Wr, _Float16* __restrict__ wrT,
    unsigned int* __restrict__ flags)
{
    __shared__ float ls[64][65];
    const int k0 = blockIdx.x * 64;
    const int n0 = blockIdx.y * 64;
    const int tid = threadIdx.x;
    if (blockIdx.x == 0 && blockIdx.y == 0) flags[tid] = 0u;
    {
        int r  = tid >> 4;
        int c4 = (tid & 15) * 4;
        #pragma unroll
        for (int p = 0; p < 4; ++p) {
            float4 v = *reinterpret_cast<const float4*>(
                &Wr[(size_t)(k0 + r + p * 16) * G4H + n0 + c4]);
            ls[r + p * 16][c4 + 0] = v.x;
            ls[r + p * 16][c4 + 1] = v.y;
            ls[r + p * 16][c4 + 2] = v.z;
            ls[r + p * 16][c4 + 3] = v.w;
        }
    }
    __syncthreads();
    {
        int rn = tid >> 2;
        int ck = (tid & 3) * 16;
        f16x8 h0, h1;
        #pragma unroll
        for (int j = 0; j < 8; ++j) {
            h0[j] = (_Float16)ls[ck + j][rn];
            h1[j] = (_Float16)ls[ck + 8 + j][rn];
        }
        _Float16* dst = &wrT[(size_t)(n0 + rn) * H_ + k0 + ck];
        *reinterpret_cast<f16x8*>(dst)     = h0;
        *reinterpret_cast<f16x8*>(dst + 8) = h1;
    }
}

// Light producer-consumer barrier: LDS-drain only, no vmcnt drain.
__device__ __forceinline__ void lds_barrier() {
    asm volatile("s_waitcnt lgkmcnt(0)" ::: "memory");
    __builtin_amdgcn_s_barrier();
    asm volatile("" ::: "memory");
}

__device__ __forceinline__ float sig_f(float x) {
    return __builtin_amdgcn_rcpf(
        1.0f + __builtin_amdgcn_exp2f(-1.442695040888963f * x));
}
__device__ __forceinline__ float tanh_f(float x) {
    return 1.0f - 2.0f * __builtin_amdgcn_rcpf(
        1.0f + __builtin_amdgcn_exp2f(2.885390081777927f * x));
}

__device__ __forceinline__ void wait_flag2(unsigned int* f) {
    while (__hip_atomic_load(f, __ATOMIC_ACQUIRE, __HIP_MEMORY_SCOPE_AGENT) < 2u)
        __builtin_amdgcn_s_sleep(2);
}

// ---------------------------------------------------------------------------
// Kernel 1+2 FUSED: blocks 0..31 = LSTM (one batch each, dispatched first,
// consume z slice-by-slice via acquire flags); blocks 32..543 = GEMM
// (z = f16(x) @ Wk + b), remapped t-slice-major so all batches' t in [0,64)
// are produced first; each (batch, slice) publishes a release flag (2 halves).
// GEMM/LSTM inner bodies are instruction-identical to R18 (same numerics).
// ---------------------------------------------------------------------------
__global__ __launch_bounds__(512, 2) void fused_gemm_lstm(
    const float* __restrict__ x, const _Float16* __restrict__ btK,
    const float* __restrict__ bias, float* __restrict__ z,
    const _Float16* __restrict__ wrT, float* __restrict__ hs,
    unsigned int* __restrict__ flags)
{
    __shared__ __align__(16) char smem[61440];   // 60 KB union
    const int bid = blockIdx.x;
    const int tid = threadIdx.x;

    if (bid >= B_) {
        // ---------------- GEMM role ----------------
        char* AsB = smem;            // 3 x 4096 B
        char* BsB = smem + 12288;    // 3 x 16384 B

        const int w   = tid >> 6;
        const int l   = tid & 63;
        const int fr  = l & 15;
        const int q   = l >> 4;

        // t-slice-major remap; sibling n-halves 8 apart (same XCD round-robin)
        const int gbid  = bid - B_;          // 0..511
        const int s     = gbid >> 6;         // t-slice 0..7
        const int i6    = gbid & 63;
        const int xx    = i6 & 7;
        const int yy    = (i6 >> 4) & 3;
        const int ntile = (i6 >> 3) & 1;
        const int bb    = xx * 4 + yy;       // batch 0..31
        const int m0    = bb * T_ + s * 64;
        const int n0    = ntile * 256;

        const int ar = tid >> 3;
        const int hc = (tid & 7) * 4;
        const int abyte = ((((hc >> 3) ^ ((ar >> 1) & 3)) << 4) | ((hc << 1) & 15));
        const float* xrow = x + (size_t)(m0 + ar) * F_ + hc;

        #define ISSUE_B(t, buf)                                               \
        {                                                                     \
            const _Float16* ck_ = btK + (size_t)(t) * (512 * 32) + n0 * 32;   \
            _Float16* bb_ = (_Float16*)(BsB + (buf) * 16384) + w * 1024;      \
            gl_lds16(ck_ + w * 1024 + l * 8,       bb_);                      \
            gl_lds16(ck_ + w * 1024 + 512 + l * 8, bb_ + 512);                \
        }

        #define LOADX(t) (*reinterpret_cast<const float4*>(xrow + (size_t)(t) * 32))

        #define WRITE_A(v, buf)                                               \
        {                                                                     \
            f16x4 hh; hh[0] = (_Float16)v.x; hh[1] = (_Float16)v.y;           \
            hh[2] = (_Float16)v.z; hh[3] = (_Float16)v.w;                     \
            *reinterpret_cast<f16x4*>(                                        \
                AsB + (buf) * 4096 + ar * 64 + abyte) = hh;                   \
        }

        #define COMPUTE(buf)                                                  \
        {                                                                     \
            f16x8 af[4], bf[2];                                               \
            _Pragma("unroll")                                                 \
            for (int i = 0; i < 4; ++i) {                                     \
                int r   = i * 16 + fr;                                        \
                int off = r * 64 + ((q ^ ((r >> 1) & 3)) << 4);               \
                af[i] = *reinterpret_cast<const f16x8*>(                      \
                    AsB + (buf) * 4096 + off);                                \
            }                                                                 \
            _Pragma("unroll")                                                 \
            for (int j = 0; j < 2; ++j) {                                     \
                int n   = w * 32 + j * 16 + fr;                               \
                int off = n * 64 + ((q ^ ((n >> 1) & 3)) << 4);               \
                bf[j] = *reinterpret_cast<const f16x8*>(                      \
                    BsB + (buf) * 16384 + off);                               \
            }                                                                 \
            _Pragma("unroll")                                                 \
            for (int i = 0; i < 4; ++i)                                       \
                _Pragma("unroll")                                             \
                for (int j = 0; j < 2; ++j)                                   \
                    acc[i][j] = __builtin_amdgcn_mfma_f32_16x16x32_f16(       \
                        af[i], bf[j], acc[i][j], 0, 0, 0);                    \
        }

        f32x4 acc[4][2] = {};
        float4 xvA, xvB;

        ISSUE_B(0, 0) xvA = LOADX(0);
        ISSUE_B(1, 1) xvB = LOADX(1);
        WRITE_A(xvA, 0)
        lds_barrier();

        int b0 = 0, b1 = 1, b2 = 2;
        for (int t = 0; t < KSTEPS; t += 2) {
            if (t + 2 < KSTEPS) { ISSUE_B(t + 2, b2) xvA = LOADX(t + 2); }
            if (t + 1 < KSTEPS) WRITE_A(xvB, b1)
            COMPUTE(b0)
            lds_barrier();
            if (t + 3 < KSTEPS) { ISSUE_B(t + 3, b0) xvB = LOADX(t + 3); }
            if (t + 2 < KSTEPS) WRITE_A(xvA, b2)
            COMPUTE(b1)
            lds_barrier();
            int tmp = b2; b2 = b1; b1 = b0; b0 = tmp;
        }
        #undef ISSUE_B
        #undef LOADX
        #undef WRITE_A
        #undef COMPUTE

        #pragma unroll
        for (int j = 0; j < 2; ++j) {
            const int nn = n0 + w * 32 + j * 16 + fr;
            const int ch = (nn & 127) * 4 + (nn >> 7);   // gate-interleaved
            const float bj = bias[nn];
            #pragma unroll
            for (int i = 0; i < 4; ++i)
                #pragma unroll
                for (int r = 0; r < 4; ++r)
                    z[(size_t)(m0 + i * 16 + q * 4 + r) * G4H + ch]
                        = acc[i][j][r] + bj;
        }

        // publish (bb, s): all threads fence their stores, then one release-add
        __threadfence();
        __syncthreads();
        if (tid == 0)
            __hip_atomic_fetch_add(&flags[(bb << 3) + s], 1u,
                                   __ATOMIC_RELEASE, __HIP_MEMORY_SCOPE_AGENT);
        return;
    }

    // ---------------- LSTM role (batch = bid) ----------------
    {
        const int b    = bid;
        const int w    = tid >> 6;
        const int lane = tid & 63;
        const int l15  = lane & 15;
        const int q    = lane >> 4;
        const int jj   = w * 16 + l15;

        _Float16 (*hA)[128] = reinterpret_cast<_Float16(*)[128]>(smem);

        f16x8 bf[4][4];
        #pragma unroll
        for (int g = 0; g < 4; ++g)
            #pragma unroll
            for (int kf = 0; kf < 4; ++kf)
                bf[g][kf] = *reinterpret_cast<const f16x8*>(
                    &wrT[(size_t)(g * H_ + jj) * H_ + kf * 32 + q * 8]);

        float cstate = 0.f;
        if (tid < 128) reinterpret_cast<unsigned int*>(hA)[tid] = 0u;

        const float* zrow  = z  + (size_t)b * T_ * G4H + jj * 4;
        float*       hbase = hs + (size_t)b * T_ * H_;

        const f32x4 zero4 = {0.f, 0.f, 0.f, 0.f};

        if (tid == 0) wait_flag2(&flags[b << 3]);   // slice 0 ready
        __syncthreads();

        float4 zP0 = *reinterpret_cast<const float4*>(zrow + (size_t)(0 << 9));
        float4 zP1 = *reinterpret_cast<const float4*>(zrow + (size_t)(1 << 9));
        float4 zP2 = *reinterpret_cast<const float4*>(zrow + (size_t)(2 << 9));
        float4 zP3 = *reinterpret_cast<const float4*>(zrow + (size_t)(3 << 9));

        #define LSTM_STEP(t, CUR, ZZ)                                         \
        {                                                                     \
            f16x8 af0 = *reinterpret_cast<const f16x8*>(&hA[CUR][0 * 32 + q * 8]);\
            f16x8 af1 = *reinterpret_cast<const f16x8*>(&hA[CUR][1 * 32 + q * 8]);\
            f16x8 af2 = *reinterpret_cast<const f16x8*>(&hA[CUR][2 * 32 + q * 8]);\
            f16x8 af3 = *reinterpret_cast<const f16x8*>(&hA[CUR][3 * 32 + q * 8]);\
            float zt0_ = ZZ.x, zt1_ = ZZ.y, zt2_ = ZZ.z, zt3_ = ZZ.w;         \
            ZZ = *reinterpret_cast<const float4*>(                            \
                zrow + (size_t)((((t) + 4) & (T_ - 1)) << 9));                \
            float gv[4];                                                      \
            _Pragma("unroll")                                                 \
            for (int g = 0; g < 4; ++g) {                                     \
                f32x4 aA = __builtin_amdgcn_mfma_f32_16x16x32_f16(            \
                    af0, bf[g][0], zero4, 0, 0, 0);                           \
                aA = __builtin_amdgcn_mfma_f32_16x16x32_f16(                  \
                    af1, bf[g][1], aA, 0, 0, 0);                              \
                f32x4 aB = __builtin_amdgcn_mfma_f32_16x16x32_f16(            \
                    af2, bf[g][2], zero4, 0, 0, 0);                           \
                aB = __builtin_amdgcn_mfma_f32_16x16x32_f16(                  \
                    af3, bf[g][3], aB, 0, 0, 0);                              \
                gv[g] = aA[0] + aB[0];                                        \
            }                                                                 \
            float iv = sig_f(gv[0] + zt0_);                                   \
            float fv = sig_f(gv[1] + zt1_);                                   \
            float cc = tanh_f(gv[2] + zt2_);                                  \
            float ov = sig_f(gv[3] + zt3_);                                   \
            cstate = fv * cstate + iv * cc;                                   \
            float h = ov * tanh_f(cstate);                                    \
            if (q == 0) {                                                     \
                hA[CUR ^ 1][jj] = (_Float16)h;                                \
                hbase[((t) << 7) + jj] = h;                                   \
            }                                                                 \
            lds_barrier();                                                    \
        }

        for (int s8 = 0; s8 < 8; ++s8) {
            // need slice s8 (reads) and s8+1 (prefetch reaches t+4)
            if (tid == 0) {
                wait_flag2(&flags[(b << 3) + s8]);
                if (s8 < 7) wait_flag2(&flags[(b << 3) + s8 + 1]);
            }
            __syncthreads();
            for (int t = s8 * 64; t < s8 * 64 + 64; t += 4) {
                LSTM_STEP(t,     0, zP0)
                LSTM_STEP(t + 1, 1, zP1)
                LSTM_STEP(t + 2, 0, zP2)
                LSTM_STEP(t + 3, 1, zP3)
            }
        }
        #undef LSTM_STEP
    }
}

// ---------------------------------------------------------------------------
// Kernel 3: out = hs @ Wd + bd
// ---------------------------------------------------------------------------
__global__ __launch_bounds__(256) void dense_out(
    const float* __restrict__ hs, const float* __restrict__ Wd,
    const float* __restrict__ bd, float* __restrict__ out)
{
    int idx = blockIdx.x * 256 + threadIdx.x;
    if (idx >= B_ * T_ * NCLS) return;
    int cls = idx % NCLS;
    int row = idx / NCLS;
    const float* h = hs + (size_t)row * H_;
    float acc = bd[cls];
    #pragma unroll 8
    for (int k = 0; k < H_; ++k) acc += h[k] * Wd[k * NCLS + cls];
    out[idx] = acc;
}

// ---------------------------------------------------------------------------
extern "C" void kernel_launch(void* const* d_in, const int* in_sizes, int n_in,
                              void* d_out, int out_size, void* d_ws, size_t ws_size,
                              hipStream_t stream)
{
    const float* x  = (const float*)d_in[0];
    const float* Wk = (const float*)d_in[1];
    const float* Wr = (const float*)d_in[2];
    const float* b  = (const float*)d_in[3];
    const float* Wd = (const float*)d_in[4];
    const float* bd = (const float*)d_in[5];
    float* out = (float*)d_out;

    float*        z     = (float*)d_ws;                        // [M, H, 4] fp32
    float*        hs    = z + (size_t)M_ * G4H;                // [M, H]  fp32
    _Float16*     btK   = (_Float16*)(hs + (size_t)M_ * H_);   // k-major, 4 MB
    _Float16*     wrT   = btK + (size_t)G4H * F_;              // [4H, H] fp16
    unsigned int* flags = (unsigned int*)(wrT + (size_t)G4H * H_); // 256 flags

    cvt_wkT<<<dim3(F_ / 64, G4H / 64), 256, 0, stream>>>(Wk, btK);
    cvt_wrT<<<dim3(H_ / 64, G4H / 64), 256, 0, stream>>>(Wr, wrT, flags);
    fused_gemm_lstm<<<B_ + 512, 512, 0, stream>>>(x, btK, b, z, wrT, hs, flags);
    int total = B_ * T_ * NCLS;
    dense_out<<<(total + 255) / 256, 256, 0, stream>>>(hs, Wd, bd, out);
}

// Round 5
// 378.116 us; speedup vs baseline: 1.6892x; 1.6892x over previous
//
#include <hip/hip_runtime.h>
#include <hip/hip_bf16.h>
#include <hip/hip_fp16.h>
#include <math.h>

// Problem dims (fixed by reference)
#define B_  32
#define T_  512
#define F_  4096
#define H_  128
#define G4H 512           // 4*H
#define NCLS 3            // NUM_CLASSES + 1
#define M_  (B_ * T_)     // 16384 rows
#define KSTEPS 128        // F_/32

typedef _Float16 f16x8 __attribute__((ext_vector_type(8)));
typedef _Float16 f16x4 __attribute__((ext_vector_type(4)));
typedef float    f32x4 __attribute__((ext_vector_type(4)));

// async global->LDS, 16B per lane; LDS dest is wave-uniform base + lane*16
__device__ __forceinline__ void gl_lds16(const _Float16* g, _Float16* l) {
    __builtin_amdgcn_global_load_lds(
        (const __attribute__((address_space(1))) void*)(g),
        (__attribute__((address_space(3))) void*)(l), 16, 0, 0);
}

// ---------------------------------------------------------------------------
// Kernel 0b: Wk [F,4H] fp32 -> btK fp16, K-MAJOR tiles with baked-in group
// swizzle: group g (8 halves) of column n stored at half-offset
//   n*32 + ((g ^ ((n>>1)&3)) << 3)
// ---------------------------------------------------------------------------
__global__ __launch_bounds__(256) void cvt_wkT(
    const float* __restrict__ Wk, _Float16* __restrict__ btK)
{
    __shared__ float ls[64][65];
    const int k0 = blockIdx.x * 64;
    const int n0 = blockIdx.y * 64;
    const int tid = threadIdx.x;

    {
        int r  = tid >> 4;
        int c4 = (tid & 15) * 4;
        #pragma unroll
        for (int p = 0; p < 4; ++p) {
            float4 v = *reinterpret_cast<const float4*>(
                &Wk[(size_t)(k0 + r + p * 16) * G4H + n0 + c4]);
            ls[r + p * 16][c4 + 0] = v.x;
            ls[r + p * 16][c4 + 1] = v.y;
            ls[r + p * 16][c4 + 2] = v.z;
            ls[r + p * 16][c4 + 3] = v.w;
        }
    }
    __syncthreads();
    {
        int rn = tid >> 2;            // n within tile 0..63
        int ck = (tid & 3) * 16;      // k within tile 0,16,32,48
        f16x8 h0, h1;
        #pragma unroll
        for (int j = 0; j < 8; ++j) {
            h0[j] = (_Float16)ls[ck + j][rn];
            h1[j] = (_Float16)ls[ck + 8 + j][rn];
        }
        const int n    = n0 + rn;
        const int kg   = k0 + ck;
        const int kblk = kg >> 5;
        const int kk   = kg & 31;           // 0 or 16
        const int g0   = kk >> 3;           // 0 or 2
        const int sw   = (n >> 1) & 3;
        _Float16* base = btK + (size_t)kblk * (512 * 32) + (size_t)n * 32;
        *reinterpret_cast<f16x8*>(base + ((g0 ^ sw) << 3))       = h0;
        *reinterpret_cast<f16x8*>(base + (((g0 + 1) ^ sw) << 3)) = h1;
    }
}

// ---------------------------------------------------------------------------
// Kernel 0c: Wr [H,4H] fp32 -> wrT [4H,H] fp16 (transpose). grid (2, 8).
// ---------------------------------------------------------------------------
__global__ __launch_bounds__(256) void cvt_wrT(
    const float* __restrict__ Wr, _Float16* __restrict__ wrT)
{
    __shared__ float ls[64][65];
    const int k0 = blockIdx.x * 64;
    const int n0 = blockIdx.y * 64;
    const int tid = threadIdx.x;
    {
        int r  = tid >> 4;
        int c4 = (tid & 15) * 4;
        #pragma unroll
        for (int p = 0; p < 4; ++p) {
            float4 v = *reinterpret_cast<const float4*>(
                &Wr[(size_t)(k0 + r + p * 16) * G4H + n0 + c4]);
            ls[r + p * 16][c4 + 0] = v.x;
            ls[r + p * 16][c4 + 1] = v.y;
            ls[r + p * 16][c4 + 2] = v.z;
            ls[r + p * 16][c4 + 3] = v.w;
        }
    }
    __syncthreads();
    {
        int rn = tid >> 2;
        int ck = (tid & 3) * 16;
        f16x8 h0, h1;
        #pragma unroll
        for (int j = 0; j < 8; ++j) {
            h0[j] = (_Float16)ls[ck + j][rn];
            h1[j] = (_Float16)ls[ck + 8 + j][rn];
        }
        _Float16* dst = &wrT[(size_t)(n0 + rn) * H_ + k0 + ck];
        *reinterpret_cast<f16x8*>(dst)     = h0;
        *reinterpret_cast<f16x8*>(dst + 8) = h1;
    }
}

// Light producer-consumer barrier: LDS-drain only, no vmcnt drain.
__device__ __forceinline__ void lds_barrier() {
    asm volatile("s_waitcnt lgkmcnt(0)" ::: "memory");
    __builtin_amdgcn_s_barrier();
    asm volatile("" ::: "memory");
}

// ---------------------------------------------------------------------------
// Kernel 1: FUSED z = f16(x) @ Wk + b.
// R20 vs R16: x prefetch deepened to distance-3 half-iters (4-reg ring,
// static indices via unroll-4). Since the x-register wait no longer drains
// the B global_load_lds queue, each half-iter now carries an explicit
// counted s_waitcnt vmcnt(4) before the barrier:
//   queue at the wait = [B(t+1)a,b | x(t+3) | B(t+2)a,b | x(t+4)]
//   retire B(t+1) => 4 younger ops remain. Never vmcnt(0) in the main loop.
// Arithmetic identical to R16 (same k-order, same RTN cvt) => z bit-exact.
// ---------------------------------------------------------------------------
__global__ __launch_bounds__(512, 4) void gemm_fused(
    const float* __restrict__ x, const _Float16* __restrict__ btK,
    const float* __restrict__ bias, float* __restrict__ z)
{
    __shared__ __align__(16) _Float16 As[3][64 * 32];    // 12 KB
    __shared__ __align__(16) _Float16 Bs[3][256 * 32];   // 48 KB

    const int tid = threadIdx.x;
    const int w   = tid >> 6;
    const int l   = tid & 63;
    const int fr  = l & 15;
    const int q   = l >> 4;

    // 512 blocks = 8 xcd * (32 m-pairs * 2 n); siblings adjacent on one XCD
    const int bid   = blockIdx.x;
    const int xcd   = bid & 7;
    const int idx   = bid >> 3;
    const int mt    = xcd * 32 + (idx >> 1);
    const int ntile = idx & 1;
    const int m0    = mt * 64;
    const int n0    = ntile * 256;

    // x staging: thread -> (row ar, cols hc..hc+3), swizzled f16 LDS layout
    const int ar = tid >> 3;
    const int hc = (tid & 7) * 4;
    const int abyte = ((((hc >> 3) ^ ((ar >> 1) & 3)) << 4) | ((hc << 1) & 15));
    const float* xrow = x + (size_t)(m0 + ar) * F_ + hc;

    #define ISSUE_B(t, buf)                                                   \
    {                                                                         \
        const _Float16* ck_ = btK + (size_t)(t) * (512 * 32) + n0 * 32;       \
        gl_lds16(ck_ + w * 1024 + l * 8,       &Bs[buf][w * 1024]);           \
        gl_lds16(ck_ + w * 1024 + 512 + l * 8, &Bs[buf][w * 1024 + 512]);     \
    }

    #define LOADX(t) (*reinterpret_cast<const float4*>(xrow + (size_t)(t) * 32))

    #define WRITE_A(v, buf)                                                   \
    {                                                                         \
        f16x4 hh; hh[0] = (_Float16)v.x; hh[1] = (_Float16)v.y;               \
        hh[2] = (_Float16)v.z; hh[3] = (_Float16)v.w;                         \
        *reinterpret_cast<f16x4*>(                                            \
            reinterpret_cast<char*>(&As[buf][0]) + ar * 64 + abyte) = hh;     \
    }

    #define COMPUTE(buf)                                                      \
    {                                                                         \
        f16x8 af[4], bf[2];                                                   \
        _Pragma("unroll")                                                     \
        for (int i = 0; i < 4; ++i) {                                         \
            int r   = i * 16 + fr;                                            \
            int off = r * 64 + ((q ^ ((r >> 1) & 3)) << 4);                   \
            af[i] = *reinterpret_cast<const f16x8*>(                          \
                reinterpret_cast<const char*>(&As[buf][0]) + off);            \
        }                                                                     \
        _Pragma("unroll")                                                     \
        for (int j = 0; j < 2; ++j) {                                         \
            int n   = w * 32 + j * 16 + fr;                                   \
            int off = n * 64 + ((q ^ ((n >> 1) & 3)) << 4);                   \
            bf[j] = *reinterpret_cast<const f16x8*>(                          \
                reinterpret_cast<const char*>(&Bs[buf][0]) + off);            \
        }                                                                     \
        _Pragma("unroll")                                                     \
        for (int i = 0; i < 4; ++i)                                           \
            _Pragma("unroll")                                                 \
            for (int j = 0; j < 2; ++j)                                       \
                acc[i][j] = __builtin_amdgcn_mfma_f32_16x16x32_f16(           \
                    af[i], bf[j], acc[i][j], 0, 0, 0);                        \
    }

    #define FENCE asm volatile("" ::: "memory");

    // half-iter: compute step t from buf b0; stage A(t+1) into b1;
    // issue B(t+2) into b2; load x(t+4) into XL; XW holds x(t+1).
    #define HALF_ITER(t, XW, XL, VMN)                                         \
    {                                                                         \
        ISSUE_B((t) + 2, b2)                                                  \
        FENCE                                                                 \
        XL = LOADX((t) + 4);                                                  \
        FENCE                                                                 \
        WRITE_A(XW, b1)                                                       \
        COMPUTE(b0)                                                           \
        asm volatile("s_waitcnt vmcnt(" #VMN ") lgkmcnt(0)" ::: "memory");    \
        __builtin_amdgcn_s_barrier();                                         \
        FENCE                                                                 \
        int _tmp = b0; b0 = b1; b1 = b2; b2 = _tmp;                           \
    }

    f32x4 acc[4][2] = {};
    float4 xq0, xq1, xq2, xq3;
    int b0 = 0, b1 = 1, b2 = 2;

    // Prologue. Queue after issues: [x0, B0a, B0b, B1a, B1b, x1, x2, x3]
    xq0 = LOADX(0);
    FENCE
    ISSUE_B(0, 0) ISSUE_B(1, 1)
    FENCE
    xq1 = LOADX(1); xq2 = LOADX(2); xq3 = LOADX(3);
    FENCE
    WRITE_A(xq0, 0)
    // retire x0 + B0 => 5 younger remain (B1ab, x1, x2, x3)
    asm volatile("s_waitcnt vmcnt(5) lgkmcnt(0)" ::: "memory");
    __builtin_amdgcn_s_barrier();
    FENCE

    // t = 0 (queue shape still carries the 3 bunched prologue x loads -> 6)
    HALF_ITER(0, xq1, xq0, 6)

    // main loop: t = 1 .. 120, steady-state counted vmcnt(4)
    for (int t = 1; t <= 117; t += 4) {
        HALF_ITER(t,     xq2, xq1, 4)
        HALF_ITER(t + 1, xq3, xq2, 4)
        HALF_ITER(t + 2, xq0, xq3, 4)
        HALF_ITER(t + 3, xq1, xq0, 4)
    }
    HALF_ITER(121, xq2, xq1, 4)
    HALF_ITER(122, xq3, xq2, 4)
    HALF_ITER(123, xq0, xq3, 4)

    // tail: t = 124..127 (no more x loads; full drains are cheap here)
    {
        ISSUE_B(126, b2)
        WRITE_A(xq1, b1)
        COMPUTE(b0)
        asm volatile("s_waitcnt vmcnt(0) lgkmcnt(0)" ::: "memory");
        __builtin_amdgcn_s_barrier();
        FENCE
        int _t = b0; b0 = b1; b1 = b2; b2 = _t;
    }
    {
        ISSUE_B(127, b2)
        WRITE_A(xq2, b1)
        COMPUTE(b0)
        asm volatile("s_waitcnt vmcnt(0) lgkmcnt(0)" ::: "memory");
        __builtin_amdgcn_s_barrier();
        FENCE
        int _t = b0; b0 = b1; b1 = b2; b2 = _t;
    }
    {
        WRITE_A(xq3, b1)
        COMPUTE(b0)
        asm volatile("s_waitcnt vmcnt(0) lgkmcnt(0)" ::: "memory");
        __builtin_amdgcn_s_barrier();
        FENCE
        int _t = b0; b0 = b1; b1 = b2; b2 = _t;
    }
    COMPUTE(b0)

    #undef ISSUE_B
    #undef LOADX
    #undef WRITE_A
    #undef COMPUTE
    #undef HALF_ITER
    #undef FENCE

    #pragma unroll
    for (int j = 0; j < 2; ++j) {
        const int nn = n0 + w * 32 + j * 16 + fr;
        const int ch = (nn & 127) * 4 + (nn >> 7);   // gate-interleaved channel
        const float bj = bias[nn];
        #pragma unroll
        for (int i = 0; i < 4; ++i)
            #pragma unroll
            for (int r = 0; r < 4; ++r)
                z[(size_t)(m0 + i * 16 + q * 4 + r) * G4H + ch]
                    = acc[i][j][r] + bj;
    }
}

// ---------------------------------------------------------------------------
// Kernel 2: MFMA LSTM recurrence — EXACT R18 body (known 228 us, bit-exact).
// ---------------------------------------------------------------------------
__device__ __forceinline__ float sig_f(float x) {
    return __builtin_amdgcn_rcpf(
        1.0f + __builtin_amdgcn_exp2f(-1.442695040888963f * x));
}
__device__ __forceinline__ float tanh_f(float x) {
    return 1.0f - 2.0f * __builtin_amdgcn_rcpf(
        1.0f + __builtin_amdgcn_exp2f(2.885390081777927f * x));
}

__global__ __launch_bounds__(512, 2) void lstm_mfma(
    const float* __restrict__ z,       // [B*T, H, 4] gate-interleaved
    const _Float16* __restrict__ wrT,  // [4H, H] = Wr^T fp16
    float* __restrict__ hs)            // [B, T, H] fp32
{
    const int b    = blockIdx.x;
    const int tid  = threadIdx.x;
    const int w    = tid >> 6;
    const int lane = tid & 63;
    const int l15  = lane & 15;
    const int q    = lane >> 4;
    const int jj   = w * 16 + l15;

    __shared__ __align__(16) _Float16 hA[2][128];

    f16x8 bf[4][4];
    #pragma unroll
    for (int g = 0; g < 4; ++g)
        #pragma unroll
        for (int kf = 0; kf < 4; ++kf)
            bf[g][kf] = *reinterpret_cast<const f16x8*>(
                &wrT[(size_t)(g * H_ + jj) * H_ + kf * 32 + q * 8]);

    float cstate = 0.f;
    if (tid < 128) reinterpret_cast<unsigned int*>(hA)[tid] = 0u;

    const float* zrow  = z  + (size_t)b * T_ * G4H + jj * 4;
    float*       hbase = hs + (size_t)b * T_ * H_;

    const f32x4 zero4 = {0.f, 0.f, 0.f, 0.f};

    float4 zP0 = *reinterpret_cast<const float4*>(zrow + (size_t)(0 << 9));
    float4 zP1 = *reinterpret_cast<const float4*>(zrow + (size_t)(1 << 9));
    float4 zP2 = *reinterpret_cast<const float4*>(zrow + (size_t)(2 << 9));
    float4 zP3 = *reinterpret_cast<const float4*>(zrow + (size_t)(3 << 9));

    __syncthreads();

    #define LSTM_STEP(t, CUR, ZZ)                                             \
    {                                                                         \
        f16x8 af0 = *reinterpret_cast<const f16x8*>(&hA[CUR][0 * 32 + q * 8]);\
        f16x8 af1 = *reinterpret_cast<const f16x8*>(&hA[CUR][1 * 32 + q * 8]);\
        f16x8 af2 = *reinterpret_cast<const f16x8*>(&hA[CUR][2 * 32 + q * 8]);\
        f16x8 af3 = *reinterpret_cast<const f16x8*>(&hA[CUR][3 * 32 + q * 8]);\
        float zt0_ = ZZ.x, zt1_ = ZZ.y, zt2_ = ZZ.z, zt3_ = ZZ.w;             \
        ZZ = *reinterpret_cast<const float4*>(                                \
            zrow + (size_t)((((t) + 4) & (T_ - 1)) << 9));                    \
        float gv[4];                                                          \
        _Pragma("unroll")                                                     \
        for (int g = 0; g < 4; ++g) {                                         \
            f32x4 aA = __builtin_amdgcn_mfma_f32_16x16x32_f16(                \
                af0, bf[g][0], zero4, 0, 0, 0);                               \
            aA = __builtin_amdgcn_mfma_f32_16x16x32_f16(                      \
                af1, bf[g][1], aA, 0, 0, 0);                                  \
            f32x4 aB = __builtin_amdgcn_mfma_f32_16x16x32_f16(                \
                af2, bf[g][2], zero4, 0, 0, 0);                               \
            aB = __builtin_amdgcn_mfma_f32_16x16x32_f16(                      \
                af3, bf[g][3], aB, 0, 0, 0);                                  \
            gv[g] = aA[0] + aB[0];                                           \
        }                                                                     \
        float iv = sig_f(gv[0] + zt0_);                                       \
        float fv = sig_f(gv[1] + zt1_);                                       \
        float cc = tanh_f(gv[2] + zt2_);                                      \
        float ov = sig_f(gv[3] + zt3_);                                       \
        cstate = fv * cstate + iv * cc;                                       \
        float h = ov * tanh_f(cstate);                                        \
        if (q == 0) {                                                         \
            hA[CUR ^ 1][jj] = (_Float16)h;                                    \
            hbase[((t) << 7) + jj] = h;                                       \
        }                                                                     \
        lds_barrier();                                                        \
    }

    for (int t = 0; t < T_; t += 4) {
        LSTM_STEP(t,     0, zP0)
        LSTM_STEP(t + 1, 1, zP1)
        LSTM_STEP(t + 2, 0, zP2)
        LSTM_STEP(t + 3, 1, zP3)
    }
    #undef LSTM_STEP
}

// ---------------------------------------------------------------------------
// Kernel 3: out = hs @ Wd + bd
// ---------------------------------------------------------------------------
__global__ __launch_bounds__(256) void dense_out(
    const float* __restrict__ hs, const float* __restrict__ Wd,
    const float* __restrict__ bd, float* __restrict__ out)
{
    int idx = blockIdx.x * 256 + threadIdx.x;
    if (idx >= B_ * T_ * NCLS) return;
    int cls = idx % NCLS;
    int row = idx / NCLS;
    const float* h = hs + (size_t)row * H_;
    float acc = bd[cls];
    #pragma unroll 8
    for (int k = 0; k < H_; ++k) acc += h[k] * Wd[k * NCLS + cls];
    out[idx] = acc;
}

// ---------------------------------------------------------------------------
extern "C" void kernel_launch(void* const* d_in, const int* in_sizes, int n_in,
                              void* d_out, int out_size, void* d_ws, size_t ws_size,
                              hipStream_t stream)
{
    const float* x  = (const float*)d_in[0];
    const float* Wk = (const float*)d_in[1];
    const float* Wr = (const float*)d_in[2];
    const float* b  = (const float*)d_in[3];
    const float* Wd = (const float*)d_in[4];
    const float* bd = (const float*)d_in[5];
    float* out = (float*)d_out;

    float*     z   = (float*)d_ws;                       // [M, H, 4] fp32
    float*     hs  = z + (size_t)M_ * G4H;               // [M, H]  fp32
    _Float16*  btK = (_Float16*)(hs + (size_t)M_ * H_);  // k-major swizzled, 4 MB
    _Float16*  wrT = btK + (size_t)G4H * F_;             // [4H, H] fp16

    cvt_wkT<<<dim3(F_ / 64, G4H / 64), 256, 0, stream>>>(Wk, btK);
    cvt_wrT<<<dim3(H_ / 64, G4H / 64), 256, 0, stream>>>(Wr, wrT);
    gemm_fused<<<512, 512, 0, stream>>>(x, btK, b, z);
    lstm_mfma<<<B_, 512, 0, stream>>>(z, wrT, hs);
    int total = B_ * T_ * NCLS;
    dense_out<<<(total + 255) / 256, 256, 0, stream>>>(hs, Wd, bd, out);
}

// Round 6
// 374.979 us; speedup vs baseline: 1.7034x; 1.0084x over previous
//
#include <hip/hip_runtime.h>
#include <hip/hip_bf16.h>
#include <hip/hip_fp16.h>
#include <math.h>

// Problem dims (fixed by reference)
#define B_  32
#define T_  512
#define F_  4096
#define H_  128
#define G4H 512           // 4*H
#define NCLS 3            // NUM_CLASSES + 1
#define M_  (B_ * T_)     // 16384 rows
#define KSTEPS 128        // F_/32

typedef _Float16 f16x8 __attribute__((ext_vector_type(8)));
typedef _Float16 f16x4 __attribute__((ext_vector_type(4)));
typedef float    f32x4 __attribute__((ext_vector_type(4)));

// ---------------------------------------------------------------------------
// Kernel 0b: Wk [F,4H] fp32 -> btK fp16, K-MAJOR tiles with baked-in group
// swizzle: group g (8 halves) of column n stored at half-offset
//   n*32 + ((g ^ ((n>>1)&3)) << 3)
// (kept from R16; now consumed by per-lane swizzled GLOBAL reads in gemm)
// ---------------------------------------------------------------------------
__global__ __launch_bounds__(256) void cvt_wkT(
    const float* __restrict__ Wk, _Float16* __restrict__ btK)
{
    __shared__ float ls[64][65];
    const int k0 = blockIdx.x * 64;
    const int n0 = blockIdx.y * 64;
    const int tid = threadIdx.x;

    {
        int r  = tid >> 4;
        int c4 = (tid & 15) * 4;
        #pragma unroll
        for (int p = 0; p < 4; ++p) {
            float4 v = *reinterpret_cast<const float4*>(
                &Wk[(size_t)(k0 + r + p * 16) * G4H + n0 + c4]);
            ls[r + p * 16][c4 + 0] = v.x;
            ls[r + p * 16][c4 + 1] = v.y;
            ls[r + p * 16][c4 + 2] = v.z;
            ls[r + p * 16][c4 + 3] = v.w;
        }
    }
    __syncthreads();
    {
        int rn = tid >> 2;            // n within tile 0..63
        int ck = (tid & 3) * 16;      // k within tile 0,16,32,48
        f16x8 h0, h1;
        #pragma unroll
        for (int j = 0; j < 8; ++j) {
            h0[j] = (_Float16)ls[ck + j][rn];
            h1[j] = (_Float16)ls[ck + 8 + j][rn];
        }
        const int n    = n0 + rn;
        const int kg   = k0 + ck;
        const int kblk = kg >> 5;
        const int kk   = kg & 31;           // 0 or 16
        const int g0   = kk >> 3;           // 0 or 2
        const int sw   = (n >> 1) & 3;
        _Float16* base = btK + (size_t)kblk * (512 * 32) + (size_t)n * 32;
        *reinterpret_cast<f16x8*>(base + ((g0 ^ sw) << 3))       = h0;
        *reinterpret_cast<f16x8*>(base + (((g0 + 1) ^ sw) << 3)) = h1;
    }
}

// ---------------------------------------------------------------------------
// Kernel 0c: Wr [H,4H] fp32 -> wrT [4H,H] fp16 (transpose). grid (2, 8).
// ---------------------------------------------------------------------------
__global__ __launch_bounds__(256) void cvt_wrT(
    const float* __restrict__ Wr, _Float16* __restrict__ wrT)
{
    __shared__ float ls[64][65];
    const int k0 = blockIdx.x * 64;
    const int n0 = blockIdx.y * 64;
    const int tid = threadIdx.x;
    {
        int r  = tid >> 4;
        int c4 = (tid & 15) * 4;
        #pragma unroll
        for (int p = 0; p < 4; ++p) {
            float4 v = *reinterpret_cast<const float4*>(
                &Wr[(size_t)(k0 + r + p * 16) * G4H + n0 + c4]);
            ls[r + p * 16][c4 + 0] = v.x;
            ls[r + p * 16][c4 + 1] = v.y;
            ls[r + p * 16][c4 + 2] = v.z;
            ls[r + p * 16][c4 + 3] = v.w;
        }
    }
    __syncthreads();
    {
        int rn = tid >> 2;
        int ck = (tid & 3) * 16;
        f16x8 h0, h1;
        #pragma unroll
        for (int j = 0; j < 8; ++j) {
            h0[j] = (_Float16)ls[ck + j][rn];
            h1[j] = (_Float16)ls[ck + 8 + j][rn];
        }
        _Float16* dst = &wrT[(size_t)(n0 + rn) * H_ + k0 + ck];
        *reinterpret_cast<f16x8*>(dst)     = h0;
        *reinterpret_cast<f16x8*>(dst + 8) = h1;
    }
}

// Light producer-consumer barrier: LDS-drain only, no vmcnt drain.
__device__ __forceinline__ void lds_barrier() {
    asm volatile("s_waitcnt lgkmcnt(0)" ::: "memory");
    __builtin_amdgcn_s_barrier();
    asm volatile("" ::: "memory");
}

// ---------------------------------------------------------------------------
// Kernel 1: FUSED z = f16(x) @ Wk + b.
// R21 vs R20 post-mortem: x-latency theory was null. New model: the LDS pipe
// (one per CU) was the most-loaded resource (96KB reads + 32KB B-DMA writes
// per CU per K-step vs ~155cy/SIMD of MFMA). B fragments are PRIVATE to each
// wave (no cross-wave reuse), so staging B through LDS was pure overhead.
// Change: B double-buffered in REGISTERS, loaded directly from btK (L2/L3-
// resident, baked swizzle = address permutation, line-coalesced).
//  - LDS shrinks 60KB -> 8KB (A double-buffer only)
//  - per wave per K-step: 4 ds_read_b128 (A) instead of 6, no B DMA writes
//  - barrier = lgkmcnt(0) only; B register waits are per-wave, after the
//    barrier, issued a full K-step ahead (>= L2 latency). No manual vmcnt.
// A-path/k-order/cvt identical to R16/R18 => z bit-exact.
// ---------------------------------------------------------------------------
__global__ __launch_bounds__(512, 4) void gemm_fused(
    const float* __restrict__ x, const _Float16* __restrict__ btK,
    const float* __restrict__ bias, float* __restrict__ z)
{
    __shared__ __align__(16) _Float16 As[2][64 * 32];    // 8 KB total

    const int tid = threadIdx.x;
    const int w   = tid >> 6;
    const int l   = tid & 63;
    const int fr  = l & 15;
    const int q   = l >> 4;

    // 512 blocks = 8 xcd * (32 m-pairs * 2 n); siblings adjacent on one XCD
    const int bid   = blockIdx.x;
    const int xcd   = bid & 7;
    const int idx   = bid >> 3;
    const int mt    = xcd * 32 + (idx >> 1);
    const int ntile = idx & 1;
    const int m0    = mt * 64;
    const int n0    = ntile * 256;

    // x staging: thread -> (row ar, cols hc..hc+3), swizzled f16 LDS layout
    const int ar = tid >> 3;
    const int hc = (tid & 7) * 4;
    const int abyte = ((((hc >> 3) ^ ((ar >> 1) & 3)) << 4) | ((hc << 1) & 15));
    const float* xrow = x + (size_t)(m0 + ar) * F_ + hc;

    // per-lane B pointers (swizzle baked into btK storage)
    const int nA = n0 + w * 32 + fr;        // j = 0 column
    const int nB = nA + 16;                 // j = 1 column
    const _Float16* bp0 = btK + (size_t)nA * 32 + ((q ^ ((nA >> 1) & 3)) << 3);
    const _Float16* bp1 = btK + (size_t)nB * 32 + ((q ^ ((nB >> 1) & 3)) << 3);

    #define LOADB(t, bfv)                                                     \
    {                                                                         \
        bfv[0] = *reinterpret_cast<const f16x8*>(bp0 + (size_t)(t) * 16384);  \
        bfv[1] = *reinterpret_cast<const f16x8*>(bp1 + (size_t)(t) * 16384);  \
    }

    #define LOADX(t) (*reinterpret_cast<const float4*>(xrow + (size_t)(t) * 32))

    #define WRITE_A(v, buf)                                                   \
    {                                                                         \
        f16x4 hh; hh[0] = (_Float16)v.x; hh[1] = (_Float16)v.y;               \
        hh[2] = (_Float16)v.z; hh[3] = (_Float16)v.w;                         \
        *reinterpret_cast<f16x4*>(                                            \
            reinterpret_cast<char*>(&As[buf][0]) + ar * 64 + abyte) = hh;     \
    }

    #define COMPUTE(buf, bfv)                                                 \
    {                                                                         \
        f16x8 af[4];                                                          \
        _Pragma("unroll")                                                     \
        for (int i = 0; i < 4; ++i) {                                         \
            int r   = i * 16 + fr;                                            \
            int off = r * 64 + ((q ^ ((r >> 1) & 3)) << 4);                   \
            af[i] = *reinterpret_cast<const f16x8*>(                          \
                reinterpret_cast<const char*>(&As[buf][0]) + off);            \
        }                                                                     \
        _Pragma("unroll")                                                     \
        for (int i = 0; i < 4; ++i)                                           \
            _Pragma("unroll")                                                 \
            for (int j = 0; j < 2; ++j)                                       \
                acc[i][j] = __builtin_amdgcn_mfma_f32_16x16x32_f16(           \
                    af[i], bfv[j], acc[i][j], 0, 0, 0);                       \
    }

    f32x4 acc[4][2] = {};
    f16x8 bfA[2], bfB[2];
    float4 xa, xb;

    // prologue
    xa = LOADX(0); xb = LOADX(1);
    LOADB(0, bfA) LOADB(1, bfB)
    WRITE_A(xa, 0)                    // compiler waits xa (counted vmcnt)
    lds_barrier();                    // A(0) visible; B loads stay in flight

    for (int t = 0; t < 126; t += 2) {
        // iter t (buf 0, bfA)
        xa = LOADX(t + 2);
        WRITE_A(xb, 1)                // stage A(t+1); waits xb only
        COMPUTE(0, bfA)
        LOADB(t + 2, bfA)             // refill after use (2-step lead)
        lds_barrier();
        // iter t+1 (buf 1, bfB)
        xb = LOADX(t + 3);
        WRITE_A(xa, 0)                // stage A(t+2)
        COMPUTE(1, bfB)
        LOADB(t + 3, bfB)
        lds_barrier();
    }
    // t = 126 (buf 0, bfA holds B(126))
    WRITE_A(xb, 1)                    // stage A(127), xb = x(127)
    COMPUTE(0, bfA)
    lds_barrier();
    // t = 127 (buf 1, bfB holds B(127))
    COMPUTE(1, bfB)

    #undef LOADB
    #undef LOADX
    #undef WRITE_A
    #undef COMPUTE

    #pragma unroll
    for (int j = 0; j < 2; ++j) {
        const int nn = n0 + w * 32 + j * 16 + fr;
        const int ch = (nn & 127) * 4 + (nn >> 7);   // gate-interleaved channel
        const float bj = bias[nn];
        #pragma unroll
        for (int i = 0; i < 4; ++i)
            #pragma unroll
            for (int r = 0; r < 4; ++r)
                z[(size_t)(m0 + i * 16 + q * 4 + r) * G4H + ch]
                    = acc[i][j][r] + bj;
    }
}

// ---------------------------------------------------------------------------
// Kernel 2: MFMA LSTM recurrence — EXACT R18 body (known 228 us, bit-exact).
// ---------------------------------------------------------------------------
__device__ __forceinline__ float sig_f(float x) {
    return __builtin_amdgcn_rcpf(
        1.0f + __builtin_amdgcn_exp2f(-1.442695040888963f * x));
}
__device__ __forceinline__ float tanh_f(float x) {
    return 1.0f - 2.0f * __builtin_amdgcn_rcpf(
        1.0f + __builtin_amdgcn_exp2f(2.885390081777927f * x));
}

__global__ __launch_bounds__(512, 2) void lstm_mfma(
    const float* __restrict__ z,       // [B*T, H, 4] gate-interleaved
    const _Float16* __restrict__ wrT,  // [4H, H] = Wr^T fp16
    float* __restrict__ hs)            // [B, T, H] fp32
{
    const int b    = blockIdx.x;
    const int tid  = threadIdx.x;
    const int w    = tid >> 6;
    const int lane = tid & 63;
    const int l15  = lane & 15;
    const int q    = lane >> 4;
    const int jj   = w * 16 + l15;

    __shared__ __align__(16) _Float16 hA[2][128];

    f16x8 bf[4][4];
    #pragma unroll
    for (int g = 0; g < 4; ++g)
        #pragma unroll
        for (int kf = 0; kf < 4; ++kf)
            bf[g][kf] = *reinterpret_cast<const f16x8*>(
                &wrT[(size_t)(g * H_ + jj) * H_ + kf * 32 + q * 8]);

    float cstate = 0.f;
    if (tid < 128) reinterpret_cast<unsigned int*>(hA)[tid] = 0u;

    const float* zrow  = z  + (size_t)b * T_ * G4H + jj * 4;
    float*       hbase = hs + (size_t)b * T_ * H_;

    const f32x4 zero4 = {0.f, 0.f, 0.f, 0.f};

    float4 zP0 = *reinterpret_cast<const float4*>(zrow + (size_t)(0 << 9));
    float4 zP1 = *reinterpret_cast<const float4*>(zrow + (size_t)(1 << 9));
    float4 zP2 = *reinterpret_cast<const float4*>(zrow + (size_t)(2 << 9));
    float4 zP3 = *reinterpret_cast<const float4*>(zrow + (size_t)(3 << 9));

    __syncthreads();

    #define LSTM_STEP(t, CUR, ZZ)                                             \
    {                                                                         \
        f16x8 af0 = *reinterpret_cast<const f16x8*>(&hA[CUR][0 * 32 + q * 8]);\
        f16x8 af1 = *reinterpret_cast<const f16x8*>(&hA[CUR][1 * 32 + q * 8]);\
        f16x8 af2 = *reinterpret_cast<const f16x8*>(&hA[CUR][2 * 32 + q * 8]);\
        f16x8 af3 = *reinterpret_cast<const f16x8*>(&hA[CUR][3 * 32 + q * 8]);\
        float zt0_ = ZZ.x, zt1_ = ZZ.y, zt2_ = ZZ.z, zt3_ = ZZ.w;             \
        ZZ = *reinterpret_cast<const float4*>(                                \
            zrow + (size_t)((((t) + 4) & (T_ - 1)) << 9));                    \
        float gv[4];                                                          \
        _Pragma("unroll")                                                     \
        for (int g = 0; g < 4; ++g) {                                         \
            f32x4 aA = __builtin_amdgcn_mfma_f32_16x16x32_f16(                \
                af0, bf[g][0], zero4, 0, 0, 0);                               \
            aA = __builtin_amdgcn_mfma_f32_16x16x32_f16(                      \
                af1, bf[g][1], aA, 0, 0, 0);                                  \
            f32x4 aB = __builtin_amdgcn_mfma_f32_16x16x32_f16(                \
                af2, bf[g][2], zero4, 0, 0, 0);                               \
            aB = __builtin_amdgcn_mfma_f32_16x16x32_f16(                      \
                af3, bf[g][3], aB, 0, 0, 0);                                  \
            gv[g] = aA[0] + aB[0];                                           \
        }                                                                     \
        float iv = sig_f(gv[0] + zt0_);                                       \
        float fv = sig_f(gv[1] + zt1_);                                       \
        float cc = tanh_f(gv[2] + zt2_);                                      \
        float ov = sig_f(gv[3] + zt3_);                                       \
        cstate = fv * cstate + iv * cc;                                       \
        float h = ov * tanh_f(cstate);                                        \
        if (q == 0) {                                                         \
            hA[CUR ^ 1][jj] = (_Float16)h;                                    \
            hbase[((t) << 7) + jj] = h;                                       \
        }                                                                     \
        lds_barrier();                                                        \
    }

    for (int t = 0; t < T_; t += 4) {
        LSTM_STEP(t,     0, zP0)
        LSTM_STEP(t + 1, 1, zP1)
        LSTM_STEP(t + 2, 0, zP2)
        LSTM_STEP(t + 3, 1, zP3)
    }
    #undef LSTM_STEP
}

// ---------------------------------------------------------------------------
// Kernel 3: out = hs @ Wd + bd
// ---------------------------------------------------------------------------
__global__ __launch_bounds__(256) void dense_out(
    const float* __restrict__ hs, const float* __restrict__ Wd,
    const float* __restrict__ bd, float* __restrict__ out)
{
    int idx = blockIdx.x * 256 + threadIdx.x;
    if (idx >= B_ * T_ * NCLS) return;
    int cls = idx % NCLS;
    int row = idx / NCLS;
    const float* h = hs + (size_t)row * H_;
    float acc = bd[cls];
    #pragma unroll 8
    for (int k = 0; k < H_; ++k) acc += h[k] * Wd[k * NCLS + cls];
    out[idx] = acc;
}

// ---------------------------------------------------------------------------
extern "C" void kernel_launch(void* const* d_in, const int* in_sizes, int n_in,
                              void* d_out, int out_size, void* d_ws, size_t ws_size,
                              hipStream_t stream)
{
    const float* x  = (const float*)d_in[0];
    const float* Wk = (const float*)d_in[1];
    const float* Wr = (const float*)d_in[2];
    const float* b  = (const float*)d_in[3];
    const float* Wd = (const float*)d_in[4];
    const float* bd = (const float*)d_in[5];
    float* out = (float*)d_out;

    float*     z   = (float*)d_ws;                       // [M, H, 4] fp32
    float*     hs  = z + (size_t)M_ * G4H;               // [M, H]  fp32
    _Float16*  btK = (_Float16*)(hs + (size_t)M_ * H_);  // k-major swizzled, 4 MB
    _Float16*  wrT = btK + (size_t)G4H * F_;             // [4H, H] fp16

    cvt_wkT<<<dim3(F_ / 64, G4H / 64), 256, 0, stream>>>(Wk, btK);
    cvt_wrT<<<dim3(H_ / 64, G4H / 64), 256, 0, stream>>>(Wr, wrT);
    gemm_fused<<<512, 512, 0, stream>>>(x, btK, b, z);
    lstm_mfma<<<B_, 512, 0, stream>>>(z, wrT, hs);
    int total = B_ * T_ * NCLS;
    dense_out<<<(total + 255) / 256, 256, 0, stream>>>(hs, Wd, bd, out);
}